// Round 14
// baseline (1901.390 us; speedup 1.0000x reference)
//
#include <hip/hip_runtime.h>
#include <cstdint>
#include <cfloat>
#include <cstddef>

#define C_   128
#define CH   64
#define B_   8
#define S_   6
#define H_   128
#define W_   192
#define HW   (H_*W_)          /* 24576 */
#define SHW  (S_*HW)          /* 147456 */
#define NPIX (B_*SHW)         /* 1179648 */
#define KTOP 100
#define CAP  6144
#define NEGV (-1e9f)
#define EPSV (1e-6f)
#define CPAD 64               /* counts padded: one counter per 256B */
#define NBIN 2048
#define FCAP 4096

// ---------------------------------------------------------------------------
// K0: prep — transpose w1 (CHxC) -> w1t_g (CxCH) + zero padded counts.
// ---------------------------------------------------------------------------
__global__ __launch_bounds__(256) void prep_kernel(
    const float* __restrict__ w1, float* __restrict__ w1t_g,
    int* __restrict__ counts)
{
    const int i = blockIdx.x * 256 + threadIdx.x;   // grid covers C_*CH = 8192
    if (i < C_ * CH) {
        const int c = i >> 6;           // [0,128)
        const int o = i & (CH - 1);     // [0,64)
        w1t_g[i] = w1[o * C_ + c];
    }
    if (i < B_ * CPAD) counts[i] = 0;
}

// ---------------------------------------------------------------------------
// K1 v8 (Round 14): R9/R10 structure (1 px/thread, 64 acc, f read ONCE)
// with w moved from the SMEM path to the VMEM path:
//   - SMEM (s_load) returns OUT-OF-ORDER; lgkmcnt can only drain to 0 =>
//     every c-iter is [16 s_loads, full drain, FMAs] — unpipelinable.
//     That drain (+32KB sL1 thrash) is the R9 gap (266us vs ~150 floor).
//   - VMEM (global_load) is IN-ORDER and vmcnt(N)-pipelinable; the asm
//     "+v" pin defeats uniformity scalarization, giving one address reg
//     per c + 16 dwordx4 with immediate offsets (~3 VALU/c overhead).
//     All-lanes-same-address = TCP broadcast fast path; w stays in vL1.
//   - f loads are NONTEMPORAL so the 600MB stream doesn't evict w.
// FMA chain identical (c asc, o asc) => bit-exact, absmax stays 0.
// NO min-waves launch_bounds (R6 spill). Spill tripwire: WRITE_SIZE.
// ---------------------------------------------------------------------------
__global__ __launch_bounds__(256) void resp_kernel(
    const float* __restrict__ feats, const float* __restrict__ sigma,
    const float* __restrict__ w1t_g, const float* __restrict__ b1,
    const float* __restrict__ w2, const float* __restrict__ b2,
    float* __restrict__ resp)
{
    __shared__ float b1s[CH];
    __shared__ float w2s[CH];
    if (threadIdx.x < CH) {
        b1s[threadIdx.x] = b1[threadIdx.x];
        w2s[threadIdx.x] = w2[threadIdx.x];
    }
    __syncthreads();

    const int plane = blockIdx.x / 96;              // b*S + s   (96 blk/plane)
    const int p0    = (blockIdx.x % 96) * 256 + threadIdx.x;
    const float* fp = feats + (size_t)plane * (size_t)(C_ * HW) + p0;

    float acc[CH];
#pragma unroll
    for (int o = 0; o < CH; ++o) acc[o] = 0.f;

#pragma unroll 4
    for (int c = 0; c < C_; ++c) {
        const float f = __builtin_nontemporal_load(fp + (size_t)c * HW);
        int cbase = c << 6;
        asm("" : "+v"(cbase));          // pin to VGPR -> VMEM (vector) path
        const float* wc = w1t_g + cbase;
#pragma unroll
        for (int o = 0; o < CH; o += 4) {
            const float4 w = *reinterpret_cast<const float4*>(wc + o);
            acc[o + 0] += w.x * f;
            acc[o + 1] += w.y * f;
            acc[o + 2] += w.z * f;
            acc[o + 3] += w.w * f;
        }
    }

    const float b2v = b2[0];
    float rx = b2v;
#pragma unroll
    for (int o = 0; o < CH; ++o) {
        const float hx = fmaxf(acc[o] + b1s[o], 0.f);
        rx += w2s[o] * hx;
    }
    const int   s   = plane % S_;
    const float sg  = sigma[s];
    resp[(size_t)plane * HW + p0] = rx * (sg * sg);
}

// ---------------------------------------------------------------------------
// K2: 3x3x3 local max -> candidates. Per-block LDS aggregation, ONE global
// atomic per block, counters padded to separate cache lines (Round-5 fix).
// ---------------------------------------------------------------------------
__global__ __launch_bounds__(256) void peak_kernel(
    const float* __restrict__ resp, int* __restrict__ counts,
    float* __restrict__ cscore, int* __restrict__ cidx)
{
    __shared__ int   lcount;
    __shared__ int   lbase;
    __shared__ float lsc[256];
    __shared__ int   lsi[256];

    if (threadIdx.x == 0) lcount = 0;
    __syncthreads();

    const int gid = blockIdx.x * 256 + threadIdx.x;   // grid covers NPIX exactly
    const int b   = gid / SHW;                        // uniform per block
    const int rem = gid - b * SHW;
    const int s   = rem / HW;                         // uniform per block
    const int p   = rem - s * HW;
    const int y   = p / W_;
    const int x   = p - y * W_;

    const float v = resp[gid];
    bool win = false;
    if (v > 0.f) {                         // is_peak requires resp > 0
        float m = NEGV;
        for (int ds = -1; ds <= 1; ++ds) {
            const int ss = s + ds;
            if (ss < 0 || ss >= S_) continue;   // NEG padding contributes nothing
            for (int dy = -1; dy <= 1; ++dy) {
                const int yy = y + dy;
                if (yy < 0 || yy >= H_) continue;
                for (int dx = -1; dx <= 1; ++dx) {
                    const int xx = x + dx;
                    if (xx < 0 || xx >= W_) continue;
                    m = fmaxf(m, resp[(b * S_ + ss) * HW + yy * W_ + xx]);
                }
            }
        }
        // m includes v itself, so m >= v and |v - m| = m - v
        win = (m - v < EPSV);
    }

    if (win) {
        const int lp = atomicAdd(&lcount, 1);   // LDS atomic — cheap
        lsc[lp] = v;
        lsi[lp] = s * HW + p;
    }
    __syncthreads();
    if (threadIdx.x == 0 && lcount > 0)
        lbase = atomicAdd(&counts[b * CPAD], lcount);  // one atomic/block, padded line
    __syncthreads();
    const int n = lcount;
    for (int i = threadIdx.x; i < n; i += 256) {
        const int pos = lbase + i;
        if (pos < CAP) {
            cscore[b * CAP + pos] = lsc[i];
            cidx[b * CAP + pos]   = lsi[i];
        }
    }
}

// ---------------------------------------------------------------------------
// K3 v3: histogram radix-select with parallel Stage-B (Round-10 win).
// Exact lax.top_k semantics: (score desc, flat idx asc).
// ---------------------------------------------------------------------------
__global__ __launch_bounds__(256) void topk_kernel(
    const float* __restrict__ cscore, const int* __restrict__ cidx,
    const int* __restrict__ counts, const float* __restrict__ sigma,
    float* __restrict__ out)
{
    __shared__ int   hist[NBIN];
    __shared__ int   psum[256];
    __shared__ float fsc[FCAP];
    __shared__ int   fid[FCAP];
    __shared__ int   nf_sh;
    __shared__ int   binB_sh;

    const int b   = blockIdx.x;
    const int tid = threadIdx.x;

    int cnt = counts[b * CPAD];
    if (cnt > CAP) cnt = CAP;
    const int need = cnt < KTOP ? cnt : KTOP;

    for (int i = tid; i < NBIN; i += 256) hist[i] = 0;
    if (tid == 0) { nf_sh = 0; binB_sh = 0; }
    __syncthreads();

    // Stage A: histogram (scores are >0 so float bits are uint-monotone)
    for (int i = tid; i < cnt; i += 256) {
        const unsigned u = __float_as_uint(cscore[b * CAP + i]);
        atomicAdd(&hist[u >> 20], 1);
    }
    __syncthreads();

    // Stage B (parallel): per-thread 8-bin descending chunks + scan;
    // unique crossing thread writes the threshold bin for rank `need`.
    int part = 0;
#pragma unroll
    for (int j = 0; j < 8; ++j) part += hist[2047 - (tid * 8 + j)];
    psum[tid] = part;
    __syncthreads();
    int v = part;
    for (int off = 1; off < 256; off <<= 1) {
        const int add = (tid >= off) ? psum[tid - off] : 0;
        __syncthreads();
        v += add;
        psum[tid] = v;
        __syncthreads();
    }
    const int base = v - part;          // candidates in higher chunks
    if (need > 0 && base < need && need <= v) {
        int cum = base, Bv = 2047 - tid * 8 - 7;
#pragma unroll
        for (int j = 0; j < 8; ++j) {
            const int bin = 2047 - (tid * 8 + j);
            cum += hist[bin];
            if (cum >= need) { Bv = bin; break; }
        }
        binB_sh = Bv;                    // exactly one thread writes
    }
    __syncthreads();
    const int B = binB_sh;

    // Stage C: compact finalists (set-based; LDS-atomic order irrelevant)
    for (int i = tid; i < cnt; i += 256) {
        const float s_ = cscore[b * CAP + i];
        const unsigned u = __float_as_uint(s_);
        if ((int)(u >> 20) >= B) {
            const int p = atomicAdd(&nf_sh, 1);
            if (p < FCAP) { fsc[p] = s_; fid[p] = cidx[b * CAP + i]; }
        }
    }
    __syncthreads();
    int nf = nf_sh;
    if (nf > FCAP) nf = FCAP;

    // Stage D: one wave, exact iterative top-100 over finalists
    if (tid < 64) {
        const int lane = tid;
        for (int k = 0; k < KTOP; ++k) {
            if (k < need) {
                float bs = -FLT_MAX;
                int   bi = 0x7fffffff;
                int   bp = -1;
                for (int i = lane; i < nf; i += 64) {
                    const float s_ = fsc[i];
                    const int   id = fid[i];
                    if (s_ > bs || (s_ == bs && id < bi)) { bs = s_; bi = id; bp = i; }
                }
#pragma unroll
                for (int off = 32; off > 0; off >>= 1) {
                    const float os = __shfl_xor(bs, off);
                    const int   oi = __shfl_xor(bi, off);
                    const int   op = __shfl_xor(bp, off);
                    if (os > bs || (os == bs && oi < bi)) { bs = os; bi = oi; bp = op; }
                }
                // winner slot is only ever scanned by lane (bp&63): same-lane
                // LDS dependency, no cross-lane sync needed
                if (bp >= 0 && (bp & 63) == lane) fsc[bp] = -FLT_MAX;
                if (lane == 0) {
                    const int sidx = bi / HW;
                    const int sp   = bi - sidx * HW;
                    const int yy   = sp / W_;
                    const int xx   = sp - yy * W_;
                    const int sc_c = sidx < 0 ? 0 : (sidx > S_ - 1 ? S_ - 1 : sidx);
                    out[b * KTOP + k]                 = bs > 0.f ? bs : 0.f;
                    out[800 + (b * KTOP + k) * 2 + 0] = (float)xx / (float)W_;
                    out[800 + (b * KTOP + k) * 2 + 1] = (float)yy / (float)H_;
                    out[2400 + b * KTOP + k]          = sigma[sc_c];
                    out[3200 + b * KTOP + k]          = (float)sp;
                }
            } else if (lane == 0) {
                // cnt < 100 fallback (not expected for this input): NEG entries
                int flat = k - cnt; if (flat < 0) flat = 0;
                const int sidx = flat / HW;
                const int sp   = flat - sidx * HW;
                const int yy   = sp / W_;
                const int xx   = sp - yy * W_;
                const int sc_c = sidx < 0 ? 0 : (sidx > S_ - 1 ? S_ - 1 : sidx);
                out[b * KTOP + k]                 = 0.f;
                out[800 + (b * KTOP + k) * 2 + 0] = (float)xx / (float)W_;
                out[800 + (b * KTOP + k) * 2 + 1] = (float)yy / (float)H_;
                out[2400 + b * KTOP + k]          = sigma[sc_c];
                out[3200 + b * KTOP + k]          = (float)sp;
            }
        }
    }
}

extern "C" void kernel_launch(void* const* d_in, const int* in_sizes, int n_in,
                              void* d_out, int out_size, void* d_ws, size_t ws_size,
                              hipStream_t stream)
{
    const float* feats = (const float*)d_in[0];
    const float* sigma = (const float*)d_in[1];
    const float* w1    = (const float*)d_in[2];
    const float* b1    = (const float*)d_in[3];
    const float* w2    = (const float*)d_in[4];
    const float* b2    = (const float*)d_in[5];
    float* out = (float*)d_out;

    char* ws = (char*)d_ws;
    float* resp   = (float*)ws;
    int*   counts = (int*)(ws + (size_t)NPIX * 4);                       // B_*CPAD ints
    float* cscore = (float*)(ws + (size_t)NPIX * 4 + (size_t)B_ * CPAD * 4);
    int*   cidx   = (int*)(ws + (size_t)NPIX * 4 + (size_t)B_ * CPAD * 4
                              + (size_t)B_ * CAP * 4);
    float* w1t_g  = (float*)(ws + (size_t)NPIX * 4 + (size_t)B_ * CPAD * 4
                              + (size_t)B_ * CAP * 4 + (size_t)B_ * CAP * 4);

    prep_kernel<<<C_ * CH / 256, 256, 0, stream>>>(w1, w1t_g, counts);
    resp_kernel<<<B_ * S_ * 96, 256, 0, stream>>>(feats, sigma, w1t_g, b1, w2, b2, resp);
    peak_kernel<<<NPIX / 256, 256, 0, stream>>>(resp, counts, cscore, cidx);
    topk_kernel<<<B_, 256, 0, stream>>>(cscore, cidx, counts, sigma, out);
}

// Round 15
// 362.286 us; speedup vs baseline: 5.2483x; 5.2483x over previous
//
#include <hip/hip_runtime.h>
#include <cstdint>
#include <cfloat>
#include <cstddef>

#define C_   128
#define CH   64
#define B_   8
#define S_   6
#define H_   128
#define W_   192
#define HW   (H_*W_)          /* 24576 */
#define SHW  (S_*HW)          /* 147456 */
#define NPIX (B_*SHW)         /* 1179648 */
#define KTOP 100
#define CAP  6144
#define NEGV (-1e9f)
#define EPSV (1e-6f)
#define CPAD 64               /* counts padded: one counter per 256B */
#define NBIN 2048
#define FCAP 4096

// ---------------------------------------------------------------------------
// K0: prep — transpose w1 (CHxC) -> w1t_g (CxCH) + zero padded counts.
// ---------------------------------------------------------------------------
__global__ __launch_bounds__(256) void prep_kernel(
    const float* __restrict__ w1, float* __restrict__ w1t_g,
    int* __restrict__ counts)
{
    const int i = blockIdx.x * 256 + threadIdx.x;   // grid covers C_*CH = 8192
    if (i < C_ * CH) {
        const int c = i >> 6;           // [0,128)
        const int o = i & (CH - 1);     // [0,64)
        w1t_g[i] = w1[o * C_ + c];
    }
    if (i < B_ * CPAD) counts[i] = 0;
}

// ---------------------------------------------------------------------------
// K1 (R10 configuration — best measured, resp ~266us):
// 1 px/thread, 64 acc VGPRs, w on the SCALAR pipe (block-uniform global
// reads -> s_load; SGPR operand feeds v_fma directly), f read exactly once,
// no LDS in the hot loop. Structural-attempt ledger (all reverted):
//   R11 LDS+scalar mix  -> 495us (shared-lgkmcnt serialization)
//   R12 all-LDS 4-wave  -> 370us (41.5KB LDS occupancy cap)
//   R13 two-sweep sL1   -> 338us (doubled f-read not hidden)
//   R14 VMEM-pinned w   -> 1788us (same-address VMEM serializes, no bcast)
// Residual gap vs 187us VALU ceiling = per-c lgkmcnt(0) SMEM drain
// (out-of-order SMEM, no partial wait; w dbuf needs 128 SGPR > limit).
// NO min-waves launch_bounds (R6: VGPR clamp + 2.1GB scratch spill).
// ---------------------------------------------------------------------------
__global__ __launch_bounds__(256) void resp_kernel(
    const float* __restrict__ feats, const float* __restrict__ sigma,
    const float* __restrict__ w1t_g, const float* __restrict__ b1,
    const float* __restrict__ w2, const float* __restrict__ b2,
    float* __restrict__ resp)
{
    __shared__ float b1s[CH];
    __shared__ float w2s[CH];
    if (threadIdx.x < CH) {
        b1s[threadIdx.x] = b1[threadIdx.x];
        w2s[threadIdx.x] = w2[threadIdx.x];
    }
    __syncthreads();

    const int plane = blockIdx.x / 96;              // b*S + s   (96 blk/plane)
    const int p0    = (blockIdx.x % 96) * 256 + threadIdx.x;
    const float* fp = feats + (size_t)plane * (size_t)(C_ * HW) + p0;

    float acc[CH];
#pragma unroll
    for (int o = 0; o < CH; ++o) acc[o] = 0.f;

#pragma unroll 4
    for (int c = 0; c < C_; ++c) {
        const float f = fp[(size_t)c * HW];         // wave: 64x4B contiguous
#pragma unroll
        for (int o = 0; o < CH; o += 4) {
            // block-uniform address -> scalar load; w.* are SGPR operands
            const float4 w = *reinterpret_cast<const float4*>(
                &w1t_g[(c << 6) + o]);
            acc[o + 0] += w.x * f;
            acc[o + 1] += w.y * f;
            acc[o + 2] += w.z * f;
            acc[o + 3] += w.w * f;
        }
    }

    const float b2v = b2[0];
    float rx = b2v;
#pragma unroll
    for (int o = 0; o < CH; ++o) {
        const float hx = fmaxf(acc[o] + b1s[o], 0.f);
        rx += w2s[o] * hx;
    }
    const int   s   = plane % S_;
    const float sg  = sigma[s];
    resp[(size_t)plane * HW + p0] = rx * (sg * sg);
}

// ---------------------------------------------------------------------------
// K2: 3x3x3 local max -> candidates. Per-block LDS aggregation, ONE global
// atomic per block, counters padded to separate cache lines (Round-5 fix).
// ---------------------------------------------------------------------------
__global__ __launch_bounds__(256) void peak_kernel(
    const float* __restrict__ resp, int* __restrict__ counts,
    float* __restrict__ cscore, int* __restrict__ cidx)
{
    __shared__ int   lcount;
    __shared__ int   lbase;
    __shared__ float lsc[256];
    __shared__ int   lsi[256];

    if (threadIdx.x == 0) lcount = 0;
    __syncthreads();

    const int gid = blockIdx.x * 256 + threadIdx.x;   // grid covers NPIX exactly
    const int b   = gid / SHW;                        // uniform per block
    const int rem = gid - b * SHW;
    const int s   = rem / HW;                         // uniform per block
    const int p   = rem - s * HW;
    const int y   = p / W_;
    const int x   = p - y * W_;

    const float v = resp[gid];
    bool win = false;
    if (v > 0.f) {                         // is_peak requires resp > 0
        float m = NEGV;
        for (int ds = -1; ds <= 1; ++ds) {
            const int ss = s + ds;
            if (ss < 0 || ss >= S_) continue;   // NEG padding contributes nothing
            for (int dy = -1; dy <= 1; ++dy) {
                const int yy = y + dy;
                if (yy < 0 || yy >= H_) continue;
                for (int dx = -1; dx <= 1; ++dx) {
                    const int xx = x + dx;
                    if (xx < 0 || xx >= W_) continue;
                    m = fmaxf(m, resp[(b * S_ + ss) * HW + yy * W_ + xx]);
                }
            }
        }
        // m includes v itself, so m >= v and |v - m| = m - v
        win = (m - v < EPSV);
    }

    if (win) {
        const int lp = atomicAdd(&lcount, 1);   // LDS atomic — cheap
        lsc[lp] = v;
        lsi[lp] = s * HW + p;
    }
    __syncthreads();
    if (threadIdx.x == 0 && lcount > 0)
        lbase = atomicAdd(&counts[b * CPAD], lcount);  // one atomic/block, padded line
    __syncthreads();
    const int n = lcount;
    for (int i = threadIdx.x; i < n; i += 256) {
        const int pos = lbase + i;
        if (pos < CAP) {
            cscore[b * CAP + pos] = lsc[i];
            cidx[b * CAP + pos]   = lsi[i];
        }
    }
}

// ---------------------------------------------------------------------------
// K3 v3: histogram radix-select with parallel Stage-B (Round-10 win).
// Exact lax.top_k semantics: (score desc, flat idx asc).
// ---------------------------------------------------------------------------
__global__ __launch_bounds__(256) void topk_kernel(
    const float* __restrict__ cscore, const int* __restrict__ cidx,
    const int* __restrict__ counts, const float* __restrict__ sigma,
    float* __restrict__ out)
{
    __shared__ int   hist[NBIN];
    __shared__ int   psum[256];
    __shared__ float fsc[FCAP];
    __shared__ int   fid[FCAP];
    __shared__ int   nf_sh;
    __shared__ int   binB_sh;

    const int b   = blockIdx.x;
    const int tid = threadIdx.x;

    int cnt = counts[b * CPAD];
    if (cnt > CAP) cnt = CAP;
    const int need = cnt < KTOP ? cnt : KTOP;

    for (int i = tid; i < NBIN; i += 256) hist[i] = 0;
    if (tid == 0) { nf_sh = 0; binB_sh = 0; }
    __syncthreads();

    // Stage A: histogram (scores are >0 so float bits are uint-monotone)
    for (int i = tid; i < cnt; i += 256) {
        const unsigned u = __float_as_uint(cscore[b * CAP + i]);
        atomicAdd(&hist[u >> 20], 1);
    }
    __syncthreads();

    // Stage B (parallel): per-thread 8-bin descending chunks + scan;
    // unique crossing thread writes the threshold bin for rank `need`.
    int part = 0;
#pragma unroll
    for (int j = 0; j < 8; ++j) part += hist[2047 - (tid * 8 + j)];
    psum[tid] = part;
    __syncthreads();
    int v = part;
    for (int off = 1; off < 256; off <<= 1) {
        const int add = (tid >= off) ? psum[tid - off] : 0;
        __syncthreads();
        v += add;
        psum[tid] = v;
        __syncthreads();
    }
    const int base = v - part;          // candidates in higher chunks
    if (need > 0 && base < need && need <= v) {
        int cum = base, Bv = 2047 - tid * 8 - 7;
#pragma unroll
        for (int j = 0; j < 8; ++j) {
            const int bin = 2047 - (tid * 8 + j);
            cum += hist[bin];
            if (cum >= need) { Bv = bin; break; }
        }
        binB_sh = Bv;                    // exactly one thread writes
    }
    __syncthreads();
    const int B = binB_sh;

    // Stage C: compact finalists (set-based; LDS-atomic order irrelevant)
    for (int i = tid; i < cnt; i += 256) {
        const float s_ = cscore[b * CAP + i];
        const unsigned u = __float_as_uint(s_);
        if ((int)(u >> 20) >= B) {
            const int p = atomicAdd(&nf_sh, 1);
            if (p < FCAP) { fsc[p] = s_; fid[p] = cidx[b * CAP + i]; }
        }
    }
    __syncthreads();
    int nf = nf_sh;
    if (nf > FCAP) nf = FCAP;

    // Stage D: one wave, exact iterative top-100 over finalists
    if (tid < 64) {
        const int lane = tid;
        for (int k = 0; k < KTOP; ++k) {
            if (k < need) {
                float bs = -FLT_MAX;
                int   bi = 0x7fffffff;
                int   bp = -1;
                for (int i = lane; i < nf; i += 64) {
                    const float s_ = fsc[i];
                    const int   id = fid[i];
                    if (s_ > bs || (s_ == bs && id < bi)) { bs = s_; bi = id; bp = i; }
                }
#pragma unroll
                for (int off = 32; off > 0; off >>= 1) {
                    const float os = __shfl_xor(bs, off);
                    const int   oi = __shfl_xor(bi, off);
                    const int   op = __shfl_xor(bp, off);
                    if (os > bs || (os == bs && oi < bi)) { bs = os; bi = oi; bp = op; }
                }
                // winner slot is only ever scanned by lane (bp&63): same-lane
                // LDS dependency, no cross-lane sync needed
                if (bp >= 0 && (bp & 63) == lane) fsc[bp] = -FLT_MAX;
                if (lane == 0) {
                    const int sidx = bi / HW;
                    const int sp   = bi - sidx * HW;
                    const int yy   = sp / W_;
                    const int xx   = sp - yy * W_;
                    const int sc_c = sidx < 0 ? 0 : (sidx > S_ - 1 ? S_ - 1 : sidx);
                    out[b * KTOP + k]                 = bs > 0.f ? bs : 0.f;
                    out[800 + (b * KTOP + k) * 2 + 0] = (float)xx / (float)W_;
                    out[800 + (b * KTOP + k) * 2 + 1] = (float)yy / (float)H_;
                    out[2400 + b * KTOP + k]          = sigma[sc_c];
                    out[3200 + b * KTOP + k]          = (float)sp;
                }
            } else if (lane == 0) {
                // cnt < 100 fallback (not expected for this input): NEG entries
                int flat = k - cnt; if (flat < 0) flat = 0;
                const int sidx = flat / HW;
                const int sp   = flat - sidx * HW;
                const int yy   = sp / W_;
                const int xx   = sp - yy * W_;
                const int sc_c = sidx < 0 ? 0 : (sidx > S_ - 1 ? S_ - 1 : sidx);
                out[b * KTOP + k]                 = 0.f;
                out[800 + (b * KTOP + k) * 2 + 0] = (float)xx / (float)W_;
                out[800 + (b * KTOP + k) * 2 + 1] = (float)yy / (float)H_;
                out[2400 + b * KTOP + k]          = sigma[sc_c];
                out[3200 + b * KTOP + k]          = (float)sp;
            }
        }
    }
}

extern "C" void kernel_launch(void* const* d_in, const int* in_sizes, int n_in,
                              void* d_out, int out_size, void* d_ws, size_t ws_size,
                              hipStream_t stream)
{
    const float* feats = (const float*)d_in[0];
    const float* sigma = (const float*)d_in[1];
    const float* w1    = (const float*)d_in[2];
    const float* b1    = (const float*)d_in[3];
    const float* w2    = (const float*)d_in[4];
    const float* b2    = (const float*)d_in[5];
    float* out = (float*)d_out;

    char* ws = (char*)d_ws;
    float* resp   = (float*)ws;
    int*   counts = (int*)(ws + (size_t)NPIX * 4);                       // B_*CPAD ints
    float* cscore = (float*)(ws + (size_t)NPIX * 4 + (size_t)B_ * CPAD * 4);
    int*   cidx   = (int*)(ws + (size_t)NPIX * 4 + (size_t)B_ * CPAD * 4
                              + (size_t)B_ * CAP * 4);
    float* w1t_g  = (float*)(ws + (size_t)NPIX * 4 + (size_t)B_ * CPAD * 4
                              + (size_t)B_ * CAP * 4 + (size_t)B_ * CAP * 4);

    prep_kernel<<<C_ * CH / 256, 256, 0, stream>>>(w1, w1t_g, counts);
    resp_kernel<<<B_ * S_ * 96, 256, 0, stream>>>(feats, sigma, w1t_g, b1, w2, b2, resp);
    peak_kernel<<<NPIX / 256, 256, 0, stream>>>(resp, counts, cscore, cidx);
    topk_kernel<<<B_, 256, 0, stream>>>(cscore, cidx, counts, sigma, out);
}

// Round 16
// 271.168 us; speedup vs baseline: 7.0119x; 1.3360x over previous
//
#include <hip/hip_runtime.h>
#include <cstdint>
#include <cfloat>
#include <cstddef>

#define C_   128
#define CH   64
#define B_   8
#define S_   6
#define H_   128
#define W_   192
#define HW   (H_*W_)          /* 24576 */
#define SHW  (S_*HW)          /* 147456 */
#define NPIX (B_*SHW)         /* 1179648 */
#define KTOP 100
#define CAP  6144
#define NEGV (-1e9f)
#define EPSV (1e-6f)
#define CPAD 64               /* counts padded: one counter per 256B */
#define NBIN 2048
#define FCAP 4096

// ---------------------------------------------------------------------------
// K0: prep — transpose w1 (CHxC) -> w1t_g (CxCH) + zero padded counts.
// ---------------------------------------------------------------------------
__global__ __launch_bounds__(256) void prep_kernel(
    const float* __restrict__ w1, float* __restrict__ w1t_g,
    int* __restrict__ counts)
{
    const int i = blockIdx.x * 256 + threadIdx.x;   // grid covers C_*CH = 8192
    if (i < C_ * CH) {
        const int c = i >> 6;           // [0,128)
        const int o = i & (CH - 1);     // [0,64)
        w1t_g[i] = w1[o * C_ + c];
    }
    if (i < B_ * CPAD) counts[i] = 0;
}

// ---------------------------------------------------------------------------
// K1 (R10 configuration — best measured, resp ~266us): 1 px/thread, 64 acc,
// w on the SCALAR pipe, f read once, no LDS in hot loop. Ledger of reverted
// attempts: R11 LDS+scalar 495 (lgkmcnt share), R12 all-LDS 370 (LDS cap),
// R13 two-sweep 338 (f re-read), R14 VMEM-pin 1788 (no same-addr bcast).
// Residual gap vs 187us VALU floor = per-c SMEM drain (structural).
// ---------------------------------------------------------------------------
__global__ __launch_bounds__(256) void resp_kernel(
    const float* __restrict__ feats, const float* __restrict__ sigma,
    const float* __restrict__ w1t_g, const float* __restrict__ b1,
    const float* __restrict__ w2, const float* __restrict__ b2,
    float* __restrict__ resp)
{
    __shared__ float b1s[CH];
    __shared__ float w2s[CH];
    if (threadIdx.x < CH) {
        b1s[threadIdx.x] = b1[threadIdx.x];
        w2s[threadIdx.x] = w2[threadIdx.x];
    }
    __syncthreads();

    const int plane = blockIdx.x / 96;              // b*S + s   (96 blk/plane)
    const int p0    = (blockIdx.x % 96) * 256 + threadIdx.x;
    const float* fp = feats + (size_t)plane * (size_t)(C_ * HW) + p0;

    float acc[CH];
#pragma unroll
    for (int o = 0; o < CH; ++o) acc[o] = 0.f;

#pragma unroll 4
    for (int c = 0; c < C_; ++c) {
        const float f = fp[(size_t)c * HW];         // wave: 64x4B contiguous
#pragma unroll
        for (int o = 0; o < CH; o += 4) {
            // block-uniform address -> scalar load; w.* are SGPR operands
            const float4 w = *reinterpret_cast<const float4*>(
                &w1t_g[(c << 6) + o]);
            acc[o + 0] += w.x * f;
            acc[o + 1] += w.y * f;
            acc[o + 2] += w.z * f;
            acc[o + 3] += w.w * f;
        }
    }

    const float b2v = b2[0];
    float rx = b2v;
#pragma unroll
    for (int o = 0; o < CH; ++o) {
        const float hx = fmaxf(acc[o] + b1s[o], 0.f);
        rx += w2s[o] * hx;
    }
    const int   s   = plane % S_;
    const float sg  = sigma[s];
    resp[(size_t)plane * HW + p0] = rx * (sg * sg);
}

// ---------------------------------------------------------------------------
// K2: 3x3x3 local max -> candidates. Per-block LDS aggregation, ONE global
// atomic per block, counters padded to separate cache lines (Round-5 fix).
// ---------------------------------------------------------------------------
__global__ __launch_bounds__(256) void peak_kernel(
    const float* __restrict__ resp, int* __restrict__ counts,
    float* __restrict__ cscore, int* __restrict__ cidx)
{
    __shared__ int   lcount;
    __shared__ int   lbase;
    __shared__ float lsc[256];
    __shared__ int   lsi[256];

    if (threadIdx.x == 0) lcount = 0;
    __syncthreads();

    const int gid = blockIdx.x * 256 + threadIdx.x;   // grid covers NPIX exactly
    const int b   = gid / SHW;                        // uniform per block
    const int rem = gid - b * SHW;
    const int s   = rem / HW;                         // uniform per block
    const int p   = rem - s * HW;
    const int y   = p / W_;
    const int x   = p - y * W_;

    const float v = resp[gid];
    bool win = false;
    if (v > 0.f) {                         // is_peak requires resp > 0
        float m = NEGV;
        for (int ds = -1; ds <= 1; ++ds) {
            const int ss = s + ds;
            if (ss < 0 || ss >= S_) continue;   // NEG padding contributes nothing
            for (int dy = -1; dy <= 1; ++dy) {
                const int yy = y + dy;
                if (yy < 0 || yy >= H_) continue;
                for (int dx = -1; dx <= 1; ++dx) {
                    const int xx = x + dx;
                    if (xx < 0 || xx >= W_) continue;
                    m = fmaxf(m, resp[(b * S_ + ss) * HW + yy * W_ + xx]);
                }
            }
        }
        // m includes v itself, so m >= v and |v - m| = m - v
        win = (m - v < EPSV);
    }

    if (win) {
        const int lp = atomicAdd(&lcount, 1);   // LDS atomic — cheap
        lsc[lp] = v;
        lsi[lp] = s * HW + p;
    }
    __syncthreads();
    if (threadIdx.x == 0 && lcount > 0)
        lbase = atomicAdd(&counts[b * CPAD], lcount);  // one atomic/block, padded line
    __syncthreads();
    const int n = lcount;
    for (int i = threadIdx.x; i < n; i += 256) {
        const int pos = lbase + i;
        if (pos < CAP) {
            cscore[b * CAP + pos] = lsc[i];
            cidx[b * CAP + pos]   = lsi[i];
        }
    }
}

// ---------------------------------------------------------------------------
// K3 v4: histogram radix-select + BITONIC Stage D (Round 16).
// When nf <= 512 (always for this input: ~150-250 finalists), fully sort
// the padded 512-entry finalist array in LDS with the exact composite
// comparator (score desc, flat idx asc) — 45 phases — then write all 100
// outputs in PARALLEL (one thread per k). Replaces the 100-iteration
// serial wave argmax + serial writes (~15-20us on 1 block/batch).
// Identical selection & order semantics to lax.top_k; iterative path kept
// verbatim as the nf>512 fallback.
// ---------------------------------------------------------------------------
__global__ __launch_bounds__(256) void topk_kernel(
    const float* __restrict__ cscore, const int* __restrict__ cidx,
    const int* __restrict__ counts, const float* __restrict__ sigma,
    float* __restrict__ out)
{
    __shared__ int   hist[NBIN];
    __shared__ int   psum[256];
    __shared__ float fsc[FCAP];
    __shared__ int   fid[FCAP];
    __shared__ int   nf_sh;
    __shared__ int   binB_sh;

    const int b   = blockIdx.x;
    const int tid = threadIdx.x;

    int cnt = counts[b * CPAD];
    if (cnt > CAP) cnt = CAP;
    const int need = cnt < KTOP ? cnt : KTOP;

    for (int i = tid; i < NBIN; i += 256) hist[i] = 0;
    if (tid == 0) { nf_sh = 0; binB_sh = 0; }
    __syncthreads();

    // Stage A: histogram (scores are >0 so float bits are uint-monotone)
    for (int i = tid; i < cnt; i += 256) {
        const unsigned u = __float_as_uint(cscore[b * CAP + i]);
        atomicAdd(&hist[u >> 20], 1);
    }
    __syncthreads();

    // Stage B (parallel): per-thread 8-bin descending chunks + scan;
    // unique crossing thread writes the threshold bin for rank `need`.
    int part = 0;
#pragma unroll
    for (int j = 0; j < 8; ++j) part += hist[2047 - (tid * 8 + j)];
    psum[tid] = part;
    __syncthreads();
    int v = part;
    for (int off = 1; off < 256; off <<= 1) {
        const int add = (tid >= off) ? psum[tid - off] : 0;
        __syncthreads();
        v += add;
        psum[tid] = v;
        __syncthreads();
    }
    const int base = v - part;          // candidates in higher chunks
    if (need > 0 && base < need && need <= v) {
        int cum = base, Bv = 2047 - tid * 8 - 7;
#pragma unroll
        for (int j = 0; j < 8; ++j) {
            const int bin = 2047 - (tid * 8 + j);
            cum += hist[bin];
            if (cum >= need) { Bv = bin; break; }
        }
        binB_sh = Bv;                    // exactly one thread writes
    }
    __syncthreads();
    const int B = binB_sh;

    // Stage C: compact finalists (set-based; LDS-atomic order irrelevant)
    for (int i = tid; i < cnt; i += 256) {
        const float s_ = cscore[b * CAP + i];
        const unsigned u = __float_as_uint(s_);
        if ((int)(u >> 20) >= B) {
            const int p = atomicAdd(&nf_sh, 1);
            if (p < FCAP) { fsc[p] = s_; fid[p] = cidx[b * CAP + i]; }
        }
    }
    __syncthreads();
    int nf = nf_sh;
    if (nf > FCAP) nf = FCAP;

    if (nf <= 512) {
        // ---- Stage D fast path: bitonic sort of 512 padded entries ----
        for (int i = tid; i < 512; i += 256) {
            if (i >= nf) { fsc[i] = -FLT_MAX; fid[i] = 0x7fffffff; }
        }
        __syncthreads();
        for (int k = 2; k <= 512; k <<= 1) {
            for (int j = k >> 1; j > 0; j >>= 1) {
#pragma unroll
                for (int half = 0; half < 2; ++half) {
                    const int i   = tid + half * 256;
                    const int ixj = i ^ j;
                    if (ixj > i) {
                        const float sa = fsc[i],  sb = fsc[ixj];
                        const int   ia = fid[i],  ib = fid[ixj];
                        // before(a,b): a ranks ahead of b per lax.top_k
                        const bool beforeAB = (sa > sb) || (sa == sb && ia < ib);
                        const bool up = ((i & k) == 0);
                        if (up ? !beforeAB : beforeAB) {
                            fsc[i] = sb; fsc[ixj] = sa;
                            fid[i] = ib; fid[ixj] = ia;
                        }
                    }
                }
                __syncthreads();
            }
        }
        // parallel output: one thread per k
        if (tid < KTOP) {
            const int k = tid;
            float scorev; int flatidx;
            if (k < need) {
                scorev  = fsc[k];
                flatidx = fid[k];
            } else {
                scorev  = 0.f;
                flatidx = k - cnt; if (flatidx < 0) flatidx = 0;
            }
            const int sidx = flatidx / HW;
            const int sp   = flatidx - sidx * HW;
            const int yy   = sp / W_;
            const int xx   = sp - yy * W_;
            const int sc_c = sidx < 0 ? 0 : (sidx > S_ - 1 ? S_ - 1 : sidx);
            out[b * KTOP + k]                 = scorev > 0.f ? scorev : 0.f;
            out[800 + (b * KTOP + k) * 2 + 0] = (float)xx / (float)W_;
            out[800 + (b * KTOP + k) * 2 + 1] = (float)yy / (float)H_;
            out[2400 + b * KTOP + k]          = sigma[sc_c];
            out[3200 + b * KTOP + k]          = (float)sp;
        }
    } else if (tid < 64) {
        // ---- Stage D fallback (nf > 512): exact iterative argmax ----
        const int lane = tid;
        for (int k = 0; k < KTOP; ++k) {
            if (k < need) {
                float bs = -FLT_MAX;
                int   bi = 0x7fffffff;
                int   bp = -1;
                for (int i = lane; i < nf; i += 64) {
                    const float s_ = fsc[i];
                    const int   id = fid[i];
                    if (s_ > bs || (s_ == bs && id < bi)) { bs = s_; bi = id; bp = i; }
                }
#pragma unroll
                for (int off = 32; off > 0; off >>= 1) {
                    const float os = __shfl_xor(bs, off);
                    const int   oi = __shfl_xor(bi, off);
                    const int   op = __shfl_xor(bp, off);
                    if (os > bs || (os == bs && oi < bi)) { bs = os; bi = oi; bp = op; }
                }
                if (bp >= 0 && (bp & 63) == lane) fsc[bp] = -FLT_MAX;
                if (lane == 0) {
                    const int sidx = bi / HW;
                    const int sp   = bi - sidx * HW;
                    const int yy   = sp / W_;
                    const int xx   = sp - yy * W_;
                    const int sc_c = sidx < 0 ? 0 : (sidx > S_ - 1 ? S_ - 1 : sidx);
                    out[b * KTOP + k]                 = bs > 0.f ? bs : 0.f;
                    out[800 + (b * KTOP + k) * 2 + 0] = (float)xx / (float)W_;
                    out[800 + (b * KTOP + k) * 2 + 1] = (float)yy / (float)H_;
                    out[2400 + b * KTOP + k]          = sigma[sc_c];
                    out[3200 + b * KTOP + k]          = (float)sp;
                }
            } else if (lane == 0) {
                int flat = k - cnt; if (flat < 0) flat = 0;
                const int sidx = flat / HW;
                const int sp   = flat - sidx * HW;
                const int yy   = sp / W_;
                const int xx   = sp - yy * W_;
                const int sc_c = sidx < 0 ? 0 : (sidx > S_ - 1 ? S_ - 1 : sidx);
                out[b * KTOP + k]                 = 0.f;
                out[800 + (b * KTOP + k) * 2 + 0] = (float)xx / (float)W_;
                out[800 + (b * KTOP + k) * 2 + 1] = (float)yy / (float)H_;
                out[2400 + b * KTOP + k]          = sigma[sc_c];
                out[3200 + b * KTOP + k]          = (float)sp;
            }
        }
    }
}

extern "C" void kernel_launch(void* const* d_in, const int* in_sizes, int n_in,
                              void* d_out, int out_size, void* d_ws, size_t ws_size,
                              hipStream_t stream)
{
    const float* feats = (const float*)d_in[0];
    const float* sigma = (const float*)d_in[1];
    const float* w1    = (const float*)d_in[2];
    const float* b1    = (const float*)d_in[3];
    const float* w2    = (const float*)d_in[4];
    const float* b2    = (const float*)d_in[5];
    float* out = (float*)d_out;

    char* ws = (char*)d_ws;
    float* resp   = (float*)ws;
    int*   counts = (int*)(ws + (size_t)NPIX * 4);                       // B_*CPAD ints
    float* cscore = (float*)(ws + (size_t)NPIX * 4 + (size_t)B_ * CPAD * 4);
    int*   cidx   = (int*)(ws + (size_t)NPIX * 4 + (size_t)B_ * CPAD * 4
                              + (size_t)B_ * CAP * 4);
    float* w1t_g  = (float*)(ws + (size_t)NPIX * 4 + (size_t)B_ * CPAD * 4
                              + (size_t)B_ * CAP * 4 + (size_t)B_ * CAP * 4);

    prep_kernel<<<C_ * CH / 256, 256, 0, stream>>>(w1, w1t_g, counts);
    resp_kernel<<<B_ * S_ * 96, 256, 0, stream>>>(feats, sigma, w1t_g, b1, w2, b2, resp);
    peak_kernel<<<NPIX / 256, 256, 0, stream>>>(resp, counts, cscore, cidx);
    topk_kernel<<<B_, 256, 0, stream>>>(cscore, cidx, counts, sigma, out);
}